// Round 14
// baseline (890.512 us; speedup 1.0000x reference)
//
#include <hip/hip_runtime.h>
#include <hip/hip_bf16.h>

#define BATCH 8
#define NPTS 4096
#define NS   1024
#define NK   32
#define CIN  128
#define C1PAD 160
#define O1   128
#define O3   256
#define MTOT 32768
#define GN_EPS 1e-5f
#define SREP 64   // stats replicas (stripe atomics to cut L2 RMW serialization)

typedef float f32x4 __attribute__((ext_vector_type(4)));
typedef float f32x2 __attribute__((ext_vector_type(2)));
typedef short s16x8 __attribute__((ext_vector_type(8)));
typedef short s16x4 __attribute__((ext_vector_type(4)));
typedef unsigned long long u64;
typedef u64 u64x2 __attribute__((ext_vector_type(2)));

static __device__ __forceinline__ unsigned short f2bf(float f){
  unsigned u = __float_as_uint(f);
  u += 0x7fffu + ((u >> 16) & 1u);
  return (unsigned short)(u >> 16);
}
static __device__ __forceinline__ float bf2f(unsigned short h){
  return __uint_as_float(((unsigned)h) << 16);
}
// exact (non-contracted) squared distance matching numpy f32: ((dx*dx)+(dy*dy))+(dz*dz)
static __device__ __forceinline__ float exact_d2(float ax,float ay,float az,float bx,float by,float bz){
  float dx=__fadd_rn(ax,-bx), dy=__fadd_rn(ay,-by), dz=__fadd_rn(az,-bz);
  return __fadd_rn(__fadd_rn(__fmul_rn(dx,dx),__fmul_rn(dy,dy)),__fmul_rn(dz,dz));
}
// wave-wide u32 max via DPP; identity is 0 (bound_ctrl injects 0 -> safe for max of non-negative)
static __device__ __forceinline__ unsigned wave_umax_dpp(unsigned v){
  unsigned o;
  o = (unsigned)__builtin_amdgcn_update_dpp(0, (int)v, 0x111, 0xf, 0xf, true); v = (o>v)?o:v; // row_shr:1
  o = (unsigned)__builtin_amdgcn_update_dpp(0, (int)v, 0x112, 0xf, 0xf, true); v = (o>v)?o:v; // row_shr:2
  o = (unsigned)__builtin_amdgcn_update_dpp(0, (int)v, 0x114, 0xf, 0xf, true); v = (o>v)?o:v; // row_shr:4
  o = (unsigned)__builtin_amdgcn_update_dpp(0, (int)v, 0x118, 0xf, 0xf, true); v = (o>v)?o:v; // row_shr:8
  o = (unsigned)__builtin_amdgcn_update_dpp(0, (int)v, 0x142, 0xf, 0xf, true); v = (o>v)?o:v; // row_bcast:15
  o = (unsigned)__builtin_amdgcn_update_dpp(0, (int)v, 0x143, 0xf, 0xf, true); v = (o>v)?o:v; // row_bcast:31
  return v;  // lane 63 holds the wave max
}
// wave-wide f32 sum via DPP (VALU pipe); lane 63 valid
static __device__ __forceinline__ float wave_fsum_dpp(float v){
  int o;
  o=__builtin_amdgcn_update_dpp(0,__float_as_int(v),0x111,0xf,0xf,true); v+=__int_as_float(o);
  o=__builtin_amdgcn_update_dpp(0,__float_as_int(v),0x112,0xf,0xf,true); v+=__int_as_float(o);
  o=__builtin_amdgcn_update_dpp(0,__float_as_int(v),0x114,0xf,0xf,true); v+=__int_as_float(o);
  o=__builtin_amdgcn_update_dpp(0,__float_as_int(v),0x118,0xf,0xf,true); v+=__int_as_float(o);
  o=__builtin_amdgcn_update_dpp(0,__float_as_int(v),0x142,0xf,0xf,true); v+=__int_as_float(o);
  o=__builtin_amdgcn_update_dpp(0,__float_as_int(v),0x143,0xf,0xf,true); v+=__int_as_float(o);
  return v;
}
static __device__ __forceinline__ float fast_sigmoid(float x){
  return __builtin_amdgcn_rcpf(1.0f + __expf(-x));   // v_rcp_f32, ~1ulp; << bf16 rounding
}
// sum the SREP replicas for (layer,b,g) -> (s1,s2)
static __device__ __forceinline__ void stats_sum(const float* __restrict__ stats,
                                                 int layer,int b,int g,float& s1,float& s2){
  const float2* p = (const float2*)(stats + (size_t)(((layer*BATCH+b)*8+g)*SREP)*2);
  float a=0.f, q=0.f;
  #pragma unroll
  for(int r=0;r<SREP;++r){ float2 v=p[r]; a+=v.x; q+=v.y; }
  s1=a; s2=q;
}

// block-range layout of the fused kernel (256 threads/block)
#define FPS_BLOCKS 8
#define FT_BASE    8
#define FT_BLOCKS  128
#define ZP_BASE    136
#define ZP_BLOCKS  8
#define WP_BASE    144
#define WP_BLOCKS  130
#define MS_BASE    274
#define MS_BLOCKS  32
#define G1_BASE    306
#define G1_BLOCKS  192
#define TOTAL_BLOCKS 498
#define WP_TASKS   (8704 + 3*BATCH*8*SREP*2)   // 8704 weights + 24576 stats zeros
#define PREP_COUNT (FT_BLOCKS + ZP_BLOCKS + WP_BLOCKS)   // 266 featT/wfrag/stats producers

// ---------------- fused: FPS + prep + STREAMED ballq+GEMM1 (persistent blocks) ----------------
__global__ __launch_bounds__(256) void k_fused(
    const float* __restrict__ coords, const float* __restrict__ features,
    const float* __restrict__ time_emb, const float* __restrict__ style,
    const float* __restrict__ w1, const float* __restrict__ w2, const float* __restrict__ w3,
    const float* __restrict__ b1,
    float* __restrict__ centers, float* __restrict__ out_time, float* __restrict__ out_style,
    unsigned short* __restrict__ featT, unsigned short* __restrict__ wfrag,
    float* __restrict__ stats, unsigned short* __restrict__ y1,
    int* __restrict__ prog, int* __restrict__ prep_done){
  union U {
    struct { float4 lc[NPTS];
             unsigned long long red[2][4] __attribute__((aligned(16))); } fps;
    float tile[64][65];
    struct { unsigned short xs[64][168]; unsigned short ys[64][136];
             int pidx[64]; float cenS[2][3]; float wsum[2][8][4]; } g1;
  };
  __shared__ U sm;
  const int blk = blockIdx.x;
  const int t = threadIdx.x;

  if(blk < FPS_BLOCKS){
    // ---- FPS: 4 waves (1/SIMD), 16 pts/lane; per-iter center store (r7-proven) +
    // progress publish every 16 iters for the streamed consumers. ----
    const int b = blk;
    const float* cb = coords + (size_t)b*3*NPTS;
    const int lane = t & 63, wid = t >> 6;
    f32x2 px2[8],py2[8],pz2[8],md2[8];
    #pragma unroll
    for(int i=0;i<8;++i){
      int p0 = t + (2*i)*256;
      px2[i]=(f32x2){cb[p0],cb[p0+256]};
      py2[i]=(f32x2){cb[NPTS+p0],cb[NPTS+p0+256]};
      pz2[i]=(f32x2){cb[2*NPTS+p0],cb[2*NPTS+p0+256]};
      md2[i]=(f32x2){3.4e38f,3.4e38f};
      sm.fps.lc[p0]     = make_float4(px2[i].x, py2[i].x, pz2[i].x, 0.f);
      sm.fps.lc[p0+256] = make_float4(px2[i].y, py2[i].y, pz2[i].y, 0.f);
    }
    float ax=cb[0], ay=cb[NPTS], az=cb[2*NPTS];
    if(t==0){
      centers[(size_t)(b*3+0)*NS]=ax;
      centers[(size_t)(b*3+1)*NS]=ay;
      centers[(size_t)(b*3+2)*NS]=az;
    }
    __syncthreads();
    for(int it=1; it<NS; ++it){
      {
        #pragma clang fp contract(off)
        f32x2 axv={ax,ax}, ayv={ay,ay}, azv={az,az};
        #pragma unroll
        for(int i=0;i<8;++i){
          f32x2 dx=px2[i]-axv, dy=py2[i]-ayv, dz=pz2[i]-azv;
          f32x2 d = dx*dx + dy*dy + dz*dz;      // pk mul/add, no contraction
          md2[i]=__builtin_elementwise_min(md2[i],d);   // v_pk_min_f32
        }
      }
      f32x2 t01=__builtin_elementwise_max(md2[0],md2[1]);
      f32x2 t23=__builtin_elementwise_max(md2[2],md2[3]);
      f32x2 t45=__builtin_elementwise_max(md2[4],md2[5]);
      f32x2 t67=__builtin_elementwise_max(md2[6],md2[7]);
      f32x2 ta=__builtin_elementwise_max(t01,t23);
      f32x2 tb=__builtin_elementwise_max(t45,t67);
      f32x2 tc=__builtin_elementwise_max(ta,tb);
      float bmax=fmaxf(tc.x,tc.y);
      unsigned bvb=(unsigned)__builtin_amdgcn_readlane((int)wave_umax_dpp(__float_as_uint(bmax)),63);
      unsigned cand=0u;
      #pragma unroll
      for(int s=15;s>=0;--s){
        float mv = (s&1)? md2[s>>1].y : md2[s>>1].x;
        cand = (__float_as_uint(mv)==bvb) ? ~(unsigned)(s*256+t) : cand;
      }
      unsigned mc = wave_umax_dpp(cand);
      const int buf=it&1;
      if(lane==63) sm.fps.red[buf][wid] = ((u64)bvb<<32) | mc;
      __syncthreads();
      u64x2 r0 = *(const u64x2*)&sm.fps.red[buf][0];
      u64x2 r1 = *(const u64x2*)&sm.fps.red[buf][2];
      u64 a0 = r0.x>r0.y?r0.x:r0.y;
      u64 a1 = r1.x>r1.y?r1.x:r1.y;
      u64 w  = a0>a1?a0:a1;
      unsigned idx = ~(unsigned)w;
      float4 c4 = sm.fps.lc[idx];
      ax=c4.x; ay=c4.y; az=c4.z;
      if(t==0){
        centers[(size_t)(b*3+0)*NS+it]=ax;
        centers[(size_t)(b*3+1)*NS+it]=ay;
        centers[(size_t)(b*3+2)*NS+it]=az;
        if((it&15)==15){
          __threadfence();   // t0 wrote all centers so far; drain before publish
          __hip_atomic_store(&prog[b], it+1, __ATOMIC_RELEASE, __HIP_MEMORY_SCOPE_AGENT);
        }
      }
    }
    return;
  }

  if(blk < ZP_BASE){
    // ---- features (B,128,N) f32 -> point-major (B,N,160) bf16 (channels 0..127) ----
    const int pb = blk - FT_BASE;
    for(int j=0;j<8;++j){
      int tid = pb*8 + j;
      int bb = tid>>7, r = tid&127, ct = r>>6, pt = r&63;
      int c0 = ct*64, p0 = pt*64;
      #pragma unroll
      for(int i=0;i<16;++i){
        int c = (t>>6)*16 + i;
        sm.tile[c][t&63] = features[((size_t)bb*CIN + c0 + c)*NPTS + p0 + (t&63)];
      }
      __syncthreads();
      #pragma unroll
      for(int i=0;i<16;++i){
        int pl = (t>>6)*16 + i;
        featT[((size_t)bb*NPTS + p0 + pl)*C1PAD + c0 + (t&63)] = f2bf(sm.tile[t&63][pl]);
      }
      __syncthreads();
    }
    __threadfence();
    __syncthreads();
    if(t==0) __hip_atomic_fetch_add(prep_done,1,__ATOMIC_RELEASE,__HIP_MEMORY_SCOPE_AGENT);
    return;
  }

  if(blk < WP_BASE){
    // ---- zero featT channels 128..159 ----
    const int zb = blk - ZP_BASE;
    s16x8 z = (s16x8){0,0,0,0,0,0,0,0};
    #pragma unroll 4
    for(int i=0;i<64;++i){
      int q = zb*16384 + i*256 + t;
      int bb = q>>14, rem = q&16383, r = rem>>2, c8 = (rem&3)*8;
      *(s16x8*)&featT[((size_t)bb*NPTS + r)*C1PAD + 128 + c8] = z;
    }
    __threadfence();
    __syncthreads();
    if(t==0) __hip_atomic_fetch_add(prep_done,1,__ATOMIC_RELEASE,__HIP_MEMORY_SCOPE_AGENT);
    return;
  }

  if(blk < MS_BASE){
    // ---- weight prep into MFMA fragment order (+ zero replicated stats) ----
    int task = (blk - WP_BASE)*256 + t;
    if(task < WP_TASKS){
      if(task >= 8704){
        stats[task - 8704] = 0.f;
      } else {
        int layer, of, cs, ln, ncs; size_t base;
        if(task < 2560){ layer=0; ncs=5; base=0;     int r=task;      of=r/320; r%=320; cs=r>>6; ln=r&63; }
        else if(task < 4608){ layer=1; ncs=4; base=20480; int r=task-2560; of=r>>8; r&=255; cs=r>>6; ln=r&63; }
        else { layer=2; ncs=4; base=36864; int r=task-4608; of=r>>8; r&=255; cs=r>>6; ln=r&63; }
        int o = of*16 + (ln&15);
        s16x8 vals;
        #pragma unroll
        for(int i=0;i<8;++i){
          int c = cs*32 + (ln>>4)*8 + i;
          float v = 0.f;
          if(layer==0){
            if(c<128) v = w1[o*131 + c + 3];
            else if(c<131) v = w1[o*131 + (c-128)];
          } else if(layer==1){
            if(c<128) v = w2[o*128 + c];
          } else {
            if(c<128) v = w3[o*128 + c];
          }
          vals[i]=(short)f2bf(v);
        }
        *(s16x8*)&wfrag[base + ((size_t)(of*ncs + cs)*64 + ln)*8] = vals;
      }
    }
    __threadfence();
    __syncthreads();
    if(t==0) __hip_atomic_fetch_add(prep_done,1,__ATOMIC_RELEASE,__HIP_MEMORY_SCOPE_AGENT);
    return;
  }

  if(blk < G1_BASE){
    // ---- time_emb slice (float4) + style copy ----
    const int mb = blk - MS_BASE;
    #pragma unroll 4
    for(int i=0;i<16;++i){
      int q = mb*4096 + i*256 + t;
      int f = q*4;
      int bb = f>>16, c = (f>>10)&63, s = f&1023;
      *(float4*)&out_time[f] = *(const float4*)&time_emb[((size_t)bb*64 + c)*NPTS + s];
    }
    if(mb==0){ out_style[t]=style[t]; out_style[256+t]=style[256+t]; }
    return;
  }

  {
    // ---- STREAMED GEMM1: 192 persistent blocks grid-stride 4096 tiles.
    // Waits: prep_done==266 once; prog[b] >= 2mt+2 per tile. Inline ballq (r8-verified). ----
    const int brel = blk - G1_BASE;
    const int lane=t&63, wid=t>>6;
    while(__hip_atomic_load(prep_done,__ATOMIC_ACQUIRE,__HIP_MEMORY_SCOPE_AGENT) < PREP_COUNT)
      __builtin_amdgcn_s_sleep(2);
    for(int tid=brel; tid<4096; tid+=G1_BLOCKS){
      const int b = tid&7, mt = tid>>3, m0 = mt*64;
      const int need = 2*mt+2;
      while(__hip_atomic_load(&prog[b],__ATOMIC_ACQUIRE,__HIP_MEMORY_SCOPE_AGENT) < need)
        __builtin_amdgcn_s_sleep(2);
      // inline ball query for the tile's 2 centers (exact reference scan order)
      if(wid<2){
        const int s0=(m0>>5)+wid;
        const float cx=centers[(size_t)(b*3+0)*NS+s0];
        const float cy=centers[(size_t)(b*3+1)*NS+s0];
        const float cz=centers[(size_t)(b*3+2)*NS+s0];
        if(lane==0){ sm.g1.cenS[wid][0]=cx; sm.g1.cenS[wid][1]=cy; sm.g1.cenS[wid][2]=cz; }
        const float* cb=coords+(size_t)b*3*NPTS;
        int cnt=0;
        for(int base=0;base<NPTS&&cnt<NK;base+=64){
          int p=base+lane;
          float d2=exact_d2(cb[p],cb[NPTS+p],cb[2*NPTS+p],cx,cy,cz);
          bool valid=d2<0.0225f;
          unsigned long long mask=__ballot(valid);
          int pos=cnt+(int)__popcll(mask&((1ull<<lane)-1ull));
          if(valid&&pos<NK) sm.g1.pidx[wid*32+pos]=p;
          cnt+=(int)__popcll(mask);
        }
        int first=sm.g1.pidx[wid*32];   // center point itself in-radius -> cnt>=1
        if(lane<NK){
          int v=(lane<cnt)?sm.g1.pidx[wid*32+lane]:first;
          sm.g1.pidx[wid*32+lane]=v;
        }
      }
      __syncthreads();
      for(int q=t;q<1280;q+=256){
        int r=q&63, ch=q>>6;
        *(s16x8*)&sm.g1.xs[r][ch*8] = *(const s16x8*)&featT[((size_t)b*NPTS + sm.g1.pidx[r])*C1PAD + ch*8];
      }
      __syncthreads();
      if(t<64){
        int p=sm.g1.pidx[t]; int sj=t>>5;
        float n0=__fadd_rn(coords[((size_t)b*3+0)*NPTS+p],-sm.g1.cenS[sj][0]);
        float n1=__fadd_rn(coords[((size_t)b*3+1)*NPTS+p],-sm.g1.cenS[sj][1]);
        float n2=__fadd_rn(coords[((size_t)b*3+2)*NPTS+p],-sm.g1.cenS[sj][2]);
        s16x4 nc={(short)f2bf(n0),(short)f2bf(n1),(short)f2bf(n2),0};
        *(s16x4*)&sm.g1.xs[t][128]=nc;
      }
      __syncthreads();
      f32x4 acc[8];
      #pragma unroll
      for(int i=0;i<8;++i) acc[i]=(f32x4){0.f,0.f,0.f,0.f};
      const unsigned short* xrow=&sm.g1.xs[wid*16+(lane&15)][0];
      #pragma unroll
      for(int cs=0;cs<5;++cs){
        s16x8 bfv=*(const s16x8*)&xrow[cs*32+(lane>>4)*8];
        #pragma unroll
        for(int of=0;of<8;++of){
          s16x8 afv=*(const s16x8*)&wfrag[((size_t)(of*5+cs)*64+lane)*8];
          acc[of]=__builtin_amdgcn_mfma_f32_16x16x32_bf16(afv,bfv,acc[of],0,0,0);
        }
      }
      #pragma unroll
      for(int of=0;of<8;++of){
        float ls=0.f,lq=0.f;
        int obase=of*16+((lane>>4)<<2);
        #pragma unroll
        for(int r=0;r<4;++r){
          float y=acc[of][r]+b1[obase+r];
          sm.g1.ys[wid*16+(lane&15)][obase+r]=f2bf(y);
          ls+=y; lq+=y*y;
        }
        ls=wave_fsum_dpp(ls); lq=wave_fsum_dpp(lq);
        if(lane==63){ sm.g1.wsum[0][of][wid]=ls; sm.g1.wsum[1][of][wid]=lq; }
      }
      __syncthreads();
      for(int q=t;q<1024;q+=256){
        int r=q&63, ch=q>>6;
        *(s16x8*)&y1[((size_t)b*MTOT+m0+r)*O1 + ch*8] = *(const s16x8*)&sm.g1.ys[r][ch*8];
      }
      if(t<8){
        float s1v=sm.g1.wsum[0][t][0]+sm.g1.wsum[0][t][1]+sm.g1.wsum[0][t][2]+sm.g1.wsum[0][t][3];
        float s2v=sm.g1.wsum[1][t][0]+sm.g1.wsum[1][t][1]+sm.g1.wsum[1][t][2]+sm.g1.wsum[1][t][3];
        int rep = mt & (SREP-1);
        atomicAdd(&stats[(((0*BATCH+b)*8+t)*SREP+rep)*2+0],s1v);
        atomicAdd(&stats[(((0*BATCH+b)*8+t)*SREP+rep)*2+1],s2v);
      }
      __syncthreads();   // LDS reuse across tiles
    }
  }
}

// ---------------- GEMM2/3: stats->norm+SiLU on load, 128->O MFMA + stats ----------------
template<int LAYER>
__global__ __launch_bounds__(256) void k_gemm23(const unsigned short* __restrict__ xin,
    const unsigned short* __restrict__ wfrag, const float* __restrict__ bias,
    const float* __restrict__ stats, const float* __restrict__ gprev,
    const float* __restrict__ beprev, unsigned short* __restrict__ yout,
    float* __restrict__ ymm, float* __restrict__ statsOut){
  const int b=blockIdx.y, mt=blockIdx.x;
  const int m0=mt*64;
  const int t=threadIdx.x, lane=t&63, wid=t>>6;
  __shared__ unsigned short xs[64][136];
  __shared__ unsigned short ys[64][136];
  __shared__ float lsc[CIN], lsh[CIN];
  __shared__ float wsum[2][8][4];
  if(t<CIN){
    int g = t>>4;                               // input layer cpg = 16
    const float cnt = 16.0f*NS*NK;
    float s1,s2; stats_sum(stats, LAYER-1, b, g, s1, s2);
    float mu=s1/cnt, var=s2/cnt-mu*mu;
    float sc=gprev[t]*rsqrtf(var+GN_EPS);
    lsc[t]=sc; lsh[t]=beprev[t]-mu*sc;
  }
  __syncthreads();
  for(int q=t;q<1024;q+=256){
    int r=q&63, ch=q>>6;
    s16x8 v = *(const s16x8*)&xin[((size_t)b*MTOT + m0 + r)*CIN + ch*8];
    s16x8 o;
    #pragma unroll
    for(int i=0;i<8;++i){
      int c=ch*8+i;
      float x = bf2f((unsigned short)v[i]);
      x = x*lsc[c] + lsh[c];
      o[i]=(short)f2bf(x*fast_sigmoid(x));
    }
    *(s16x8*)&xs[r][ch*8]=o;
  }
  __syncthreads();
  const unsigned short* xrow=&xs[wid*16+(lane&15)][0];
  s16x8 bfv[4];
  #pragma unroll
  for(int cs=0;cs<4;++cs) bfv[cs]=*(const s16x8*)&xrow[cs*32+(lane>>4)*8];
  const int NPH=(LAYER==2)?2:1;
  #pragma unroll
  for(int ph=0; ph<NPH; ++ph){
    f32x4 acc[8];
    #pragma unroll
    for(int i=0;i<8;++i) acc[i]=(f32x4){0.f,0.f,0.f,0.f};
    #pragma unroll
    for(int cs=0;cs<4;++cs){
      #pragma unroll
      for(int of=0;of<8;++of){
        int ofg=ph*8+of;
        s16x8 afv=*(const s16x8*)&wfrag[((size_t)(ofg*4+cs)*64+lane)*8];
        acc[of]=__builtin_amdgcn_mfma_f32_16x16x32_bf16(afv,bfv[cs],acc[of],0,0,0);
      }
    }
    #pragma unroll
    for(int of=0;of<8;++of){
      float ls=0.f,lq=0.f;
      int lobase=of*16+((lane>>4)<<2);
      #pragma unroll
      for(int r=0;r<4;++r){
        float y=acc[of][r]+bias[ph*128+lobase+r];
        ys[wid*16+(lane&15)][lobase+r]=f2bf(y);
        ls+=y; lq+=y*y;
      }
      ls=wave_fsum_dpp(ls); lq=wave_fsum_dpp(lq);
      if(lane==63){ wsum[0][of][wid]=ls; wsum[1][of][wid]=lq; }
    }
    __syncthreads();
    if constexpr(LAYER==1){
      for(int q=t;q<1024;q+=256){
        int r=q&63, ch=q>>6;
        *(s16x8*)&yout[((size_t)b*MTOT+m0+r)*O1 + ch*8] = *(const s16x8*)&ys[r][ch*8];
      }
    } else {
      // per-(s,c) min/max over 32 k-rows (silu quasiconvex: max silu = max(silu(min), silu(max)))
      int c = t&127, sg = t>>7;
      float mn=3.4e38f, mx=-3.4e38f;
      #pragma unroll 8
      for(int k=0;k<32;++k){
        float v = bf2f(ys[sg*32+k][c]);
        mn=fminf(mn,v); mx=fmaxf(mx,v);
      }
      *(float2*)&ymm[(((size_t)b*NS + mt*2 + sg)*512) + (size_t)(ph*128+c)*2] = make_float2(mn,mx);
    }
    if(t<8){
      float s1v=wsum[0][t][0]+wsum[0][t][1]+wsum[0][t][2]+wsum[0][t][3];
      float s2v=wsum[1][t][0]+wsum[1][t][1]+wsum[1][t][2]+wsum[1][t][3];
      int g = (LAYER==2) ? (ph*4 + (t>>1)) : t;
      int rep = mt & (SREP-1);
      atomicAdd(&statsOut[(((LAYER*BATCH+b)*8+g)*SREP+rep)*2+0],s1v);
      atomicAdd(&statsOut[(((LAYER*BATCH+b)*8+g)*SREP+rep)*2+1],s2v);
    }
    if(ph+1<NPH) __syncthreads();
  }
}

// ---------------- final: norm3+SiLU on (min,max) + transposed coalesced writes ----------------
__global__ __launch_bounds__(256) void k_out(const float* __restrict__ ymm,
    const float* __restrict__ stats, const float* __restrict__ g3,
    const float* __restrict__ be3, float* __restrict__ out){
  const int b=blockIdx.z, st=blockIdx.x;
  const int t=threadIdx.x;
  __shared__ float outT[256][33];
  const int c=t, g=c>>5;                         // layer3 cpg = 32
  const float cnt = 32.0f*NS*NK;
  float s1,s2; stats_sum(stats, 2, b, g, s1, s2);
  float mu=s1/cnt, var=s2/cnt-mu*mu;
  float sc=g3[c]*rsqrtf(var+GN_EPS);
  float sh=be3[c]-mu*sc;
  for(int si=0;si<32;++si){
    int s=st*32+si;
    float2 v=*(const float2*)&ymm[((size_t)b*NS+s)*512 + (size_t)c*2];
    float za=v.x*sc+sh, zb=v.y*sc+sh;
    float fa=za*fast_sigmoid(za);
    float fb=zb*fast_sigmoid(zb);
    outT[c][si]=fmaxf(fa,fb);
  }
  __syncthreads();
  #pragma unroll
  for(int i=0;i<32;++i){
    int row=(t>>5)+i*8;
    out[((size_t)(b*256+row))*NS + st*32 + (t&31)] = outT[row][t&31];
  }
}

extern "C" void kernel_launch(void* const* d_in, const int* in_sizes, int n_in,
                              void* d_out, int out_size, void* d_ws, size_t ws_size,
                              hipStream_t stream){
  const float* features=(const float*)d_in[0];
  const float* coords=(const float*)d_in[1];
  const float* time_emb=(const float*)d_in[2];
  const float* style=(const float*)d_in[3];
  const float* w1=(const float*)d_in[4];
  const float* b1=(const float*)d_in[5];
  const float* g1=(const float*)d_in[6];
  const float* be1=(const float*)d_in[7];
  const float* w2=(const float*)d_in[8];
  const float* b2=(const float*)d_in[9];
  const float* g2=(const float*)d_in[10];
  const float* be2=(const float*)d_in[11];
  const float* w3=(const float*)d_in[12];
  const float* b3=(const float*)d_in[13];
  const float* g3=(const float*)d_in[14];
  const float* be3=(const float*)d_in[15];

  float* out0=(float*)d_out;
  float* out_centers=out0 + (size_t)BATCH*O3*NS;
  float* out_time=out_centers + (size_t)BATCH*3*NS;
  float* out_style=out_time + (size_t)BATCH*64*NS;

  char* ws=(char*)d_ws;
  unsigned short* featT=(unsigned short*)(ws + 1179648);
  unsigned short* wfrag=(unsigned short*)(ws + 11796480);
  int* ctr=(int*)(ws + 11935744);                        // prog[8] + prep_done
  float* stats=(float*)(ws + 11939840);                  // 96 KB (3×8×8×SREP×2 f32)
  float* ymm=(float*)(ws + 12582912);                    // 16 MB (b,s,256ch × {min,max})
  unsigned short* y1=(unsigned short*)(ws + 33554432);   // 64 MB
  unsigned short* y2=(unsigned short*)(ws + 100663296);  // 64 MB

  hipMemsetAsync(ctr, 0, 64, stream);                    // zero prog[] + prep_done (graph-legal)
  k_fused<<<TOTAL_BLOCKS,256,0,stream>>>(coords,features,time_emb,style,w1,w2,w3,b1,
                                         out_centers,out_time,out_style,featT,wfrag,stats,y1,
                                         ctr,ctr+8);
  k_gemm23<1><<<dim3(512,BATCH),256,0,stream>>>(y1,wfrag+20480,b2,stats,g1,be1,y2,ymm,stats);
  k_gemm23<2><<<dim3(512,BATCH),256,0,stream>>>(y2,wfrag+36864,b3,stats,g2,be2,y2,ymm,stats);
  k_out<<<dim3(32,1,BATCH),256,0,stream>>>(ymm,stats,g3,be3,out0);
}

// Round 15
// 870.133 us; speedup vs baseline: 1.0234x; 1.0234x over previous
//
#include <hip/hip_runtime.h>
#include <hip/hip_bf16.h>

#define BATCH 8
#define NPTS 4096
#define NS   1024
#define NK   32
#define CIN  128
#define C1PAD 160
#define O1   128
#define O3   256
#define MTOT 32768
#define GN_EPS 1e-5f
#define SREP 64   // stats replicas (stripe atomics to cut L2 RMW serialization)

typedef float f32x4 __attribute__((ext_vector_type(4)));
typedef float f32x2 __attribute__((ext_vector_type(2)));
typedef short s16x8 __attribute__((ext_vector_type(8)));
typedef short s16x4 __attribute__((ext_vector_type(4)));
typedef unsigned long long u64;
typedef u64 u64x2 __attribute__((ext_vector_type(2)));

static __device__ __forceinline__ unsigned short f2bf(float f){
  unsigned u = __float_as_uint(f);
  u += 0x7fffu + ((u >> 16) & 1u);
  return (unsigned short)(u >> 16);
}
static __device__ __forceinline__ float bf2f(unsigned short h){
  return __uint_as_float(((unsigned)h) << 16);
}
// exact (non-contracted) squared distance matching numpy f32: ((dx*dx)+(dy*dy))+(dz*dz)
static __device__ __forceinline__ float exact_d2(float ax,float ay,float az,float bx,float by,float bz){
  float dx=__fadd_rn(ax,-bx), dy=__fadd_rn(ay,-by), dz=__fadd_rn(az,-bz);
  return __fadd_rn(__fadd_rn(__fmul_rn(dx,dx),__fmul_rn(dy,dy)),__fmul_rn(dz,dz));
}
// wave-wide u32 max via DPP; identity is 0 (bound_ctrl injects 0 -> safe for max of non-negative)
static __device__ __forceinline__ unsigned wave_umax_dpp(unsigned v){
  unsigned o;
  o = (unsigned)__builtin_amdgcn_update_dpp(0, (int)v, 0x111, 0xf, 0xf, true); v = (o>v)?o:v; // row_shr:1
  o = (unsigned)__builtin_amdgcn_update_dpp(0, (int)v, 0x112, 0xf, 0xf, true); v = (o>v)?o:v; // row_shr:2
  o = (unsigned)__builtin_amdgcn_update_dpp(0, (int)v, 0x114, 0xf, 0xf, true); v = (o>v)?o:v; // row_shr:4
  o = (unsigned)__builtin_amdgcn_update_dpp(0, (int)v, 0x118, 0xf, 0xf, true); v = (o>v)?o:v; // row_shr:8
  o = (unsigned)__builtin_amdgcn_update_dpp(0, (int)v, 0x142, 0xf, 0xf, true); v = (o>v)?o:v; // row_bcast:15
  o = (unsigned)__builtin_amdgcn_update_dpp(0, (int)v, 0x143, 0xf, 0xf, true); v = (o>v)?o:v; // row_bcast:31
  return v;  // lane 63 holds the wave max
}
// wave-wide f32 sum via DPP (VALU pipe); lane 63 valid
static __device__ __forceinline__ float wave_fsum_dpp(float v){
  int o;
  o=__builtin_amdgcn_update_dpp(0,__float_as_int(v),0x111,0xf,0xf,true); v+=__int_as_float(o);
  o=__builtin_amdgcn_update_dpp(0,__float_as_int(v),0x112,0xf,0xf,true); v+=__int_as_float(o);
  o=__builtin_amdgcn_update_dpp(0,__float_as_int(v),0x114,0xf,0xf,true); v+=__int_as_float(o);
  o=__builtin_amdgcn_update_dpp(0,__float_as_int(v),0x118,0xf,0xf,true); v+=__int_as_float(o);
  o=__builtin_amdgcn_update_dpp(0,__float_as_int(v),0x142,0xf,0xf,true); v+=__int_as_float(o);
  o=__builtin_amdgcn_update_dpp(0,__float_as_int(v),0x143,0xf,0xf,true); v+=__int_as_float(o);
  return v;
}
static __device__ __forceinline__ float fast_sigmoid(float x){
  return __builtin_amdgcn_rcpf(1.0f + __expf(-x));   // v_rcp_f32, ~1ulp; << bf16 rounding
}
// sum the SREP replicas for (layer,b,g) -> (s1,s2)
static __device__ __forceinline__ void stats_sum(const float* __restrict__ stats,
                                                 int layer,int b,int g,float& s1,float& s2){
  const float2* p = (const float2*)(stats + (size_t)(((layer*BATCH+b)*8+g)*SREP)*2);
  float a=0.f, q=0.f;
  #pragma unroll
  for(int r=0;r<SREP;++r){ float2 v=p[r]; a+=v.x; q+=v.y; }
  s1=a; s2=q;
}

// block-range layout of the fused kernel (256 threads/block)
#define FPS_BLOCKS 8
#define FT_BASE    8
#define FT_BLOCKS  128
#define ZP_BASE    136
#define ZP_BLOCKS  8
#define WP_BASE    144
#define WP_BLOCKS  130
#define MS_BASE    274
#define MS_BLOCKS  32
#define TOTAL_BLOCKS 306
#define WP_TASKS   (8704 + 3*BATCH*8*SREP*2)   // 8704 weights + 24576 stats zeros

// ---------------- fused: FPS (blocks 0..7, 4 waves) + all prep on idle CUs ----------------
__global__ __launch_bounds__(256) void k_fused(
    const float* __restrict__ coords, const float* __restrict__ features,
    const float* __restrict__ time_emb, const float* __restrict__ style,
    const float* __restrict__ w1, const float* __restrict__ w2, const float* __restrict__ w3,
    float* __restrict__ centers, float* __restrict__ out_time, float* __restrict__ out_style,
    unsigned short* __restrict__ featT, unsigned short* __restrict__ wfrag,
    float* __restrict__ stats){
  union U {
    struct { float4 lc[NPTS];
             unsigned long long red[2][4] __attribute__((aligned(16)));
             float cx_[NS]; float cy_[NS]; float cz_[NS]; } fps;
    float tile[64][65];
  };
  __shared__ U sm;
  const int blk = blockIdx.x;
  const int t = threadIdx.x;

  if(blk < FPS_BLOCKS){
    // ---- FPS: 4 waves (1/SIMD), 16 pts/lane; no global ops in the loop.
    // Structural floor: invariant across 8/4/1-wave, store placement, payload (r5-r12). ----
    const int b = blk;
    const float* cb = coords + (size_t)b*3*NPTS;
    const int lane = t & 63, wid = t >> 6;
    f32x2 px2[8],py2[8],pz2[8],md2[8];
    #pragma unroll
    for(int i=0;i<8;++i){
      int p0 = t + (2*i)*256;
      px2[i]=(f32x2){cb[p0],cb[p0+256]};
      py2[i]=(f32x2){cb[NPTS+p0],cb[NPTS+p0+256]};
      pz2[i]=(f32x2){cb[2*NPTS+p0],cb[2*NPTS+p0+256]};
      md2[i]=(f32x2){3.4e38f,3.4e38f};
      sm.fps.lc[p0]     = make_float4(px2[i].x, py2[i].x, pz2[i].x, 0.f);
      sm.fps.lc[p0+256] = make_float4(px2[i].y, py2[i].y, pz2[i].y, 0.f);
    }
    float ax=cb[0], ay=cb[NPTS], az=cb[2*NPTS];
    if(t==0){ sm.fps.cx_[0]=ax; sm.fps.cy_[0]=ay; sm.fps.cz_[0]=az; }
    __syncthreads();
    for(int it=1; it<NS; ++it){
      {
        #pragma clang fp contract(off)
        f32x2 axv={ax,ax}, ayv={ay,ay}, azv={az,az};
        #pragma unroll
        for(int i=0;i<8;++i){
          f32x2 dx=px2[i]-axv, dy=py2[i]-ayv, dz=pz2[i]-azv;
          f32x2 d = dx*dx + dy*dy + dz*dz;      // pk mul/add, no contraction
          md2[i]=__builtin_elementwise_min(md2[i],d);   // v_pk_min_f32
        }
      }
      f32x2 t01=__builtin_elementwise_max(md2[0],md2[1]);
      f32x2 t23=__builtin_elementwise_max(md2[2],md2[3]);
      f32x2 t45=__builtin_elementwise_max(md2[4],md2[5]);
      f32x2 t67=__builtin_elementwise_max(md2[6],md2[7]);
      f32x2 ta=__builtin_elementwise_max(t01,t23);
      f32x2 tb=__builtin_elementwise_max(t45,t67);
      f32x2 tc=__builtin_elementwise_max(ta,tb);
      float bmax=fmaxf(tc.x,tc.y);
      unsigned bvb=(unsigned)__builtin_amdgcn_readlane((int)wave_umax_dpp(__float_as_uint(bmax)),63);
      // per-lane smallest matching global idx, as ~idx (0 = no match); descending slot order
      unsigned cand=0u;
      #pragma unroll
      for(int s=15;s>=0;--s){
        float mv = (s&1)? md2[s>>1].y : md2[s>>1].x;
        cand = (__float_as_uint(mv)==bvb) ? ~(unsigned)(s*256+t) : cand;
      }
      // wave max of ~idx  ==  min idx among matches (identity 0 is safe)
      unsigned mc = wave_umax_dpp(cand);
      const int buf=it&1;
      if(lane==63) sm.fps.red[buf][wid] = ((u64)bvb<<32) | mc;
      __syncthreads();   // single barrier per iteration (red[] double-buffered)
      u64x2 r0 = *(const u64x2*)&sm.fps.red[buf][0];
      u64x2 r1 = *(const u64x2*)&sm.fps.red[buf][2];
      u64 a0 = r0.x>r0.y?r0.x:r0.y;
      u64 a1 = r1.x>r1.y?r1.x:r1.y;
      u64 w  = a0>a1?a0:a1;
      unsigned idx = ~(unsigned)w;
      float4 c4 = sm.fps.lc[idx];               // single broadcast ds_read_b128
      ax=c4.x; ay=c4.y; az=c4.z;
      if(t==0){ sm.fps.cx_[it]=ax; sm.fps.cy_[it]=ay; sm.fps.cz_[it]=az; }
    }
    // bulk coalesced flush of all 1024 centers (off the critical loop)
    __syncthreads();
    for(int i=t;i<NS;i+=256){
      centers[(size_t)(b*3+0)*NS+i]=sm.fps.cx_[i];
      centers[(size_t)(b*3+1)*NS+i]=sm.fps.cy_[i];
      centers[(size_t)(b*3+2)*NS+i]=sm.fps.cz_[i];
    }
    return;
  }

  if(blk < ZP_BASE){
    // ---- features (B,128,N) f32 -> point-major (B,N,160) bf16 (channels 0..127) ----
    const int pb = blk - FT_BASE;
    for(int j=0;j<8;++j){
      int tid = pb*8 + j;
      int bb = tid>>7, r = tid&127, ct = r>>6, pt = r&63;
      int c0 = ct*64, p0 = pt*64;
      #pragma unroll
      for(int i=0;i<16;++i){
        int c = (t>>6)*16 + i;
        sm.tile[c][t&63] = features[((size_t)bb*CIN + c0 + c)*NPTS + p0 + (t&63)];
      }
      __syncthreads();
      #pragma unroll
      for(int i=0;i<16;++i){
        int pl = (t>>6)*16 + i;
        featT[((size_t)bb*NPTS + p0 + pl)*C1PAD + c0 + (t&63)] = f2bf(sm.tile[t&63][pl]);
      }
      __syncthreads();
    }
    return;
  }

  if(blk < WP_BASE){
    // ---- zero featT channels 128..159 ----
    const int zb = blk - ZP_BASE;
    s16x8 z = (s16x8){0,0,0,0,0,0,0,0};
    #pragma unroll 4
    for(int i=0;i<64;++i){
      int q = zb*16384 + i*256 + t;
      int bb = q>>14, rem = q&16383, r = rem>>2, c8 = (rem&3)*8;
      *(s16x8*)&featT[((size_t)bb*NPTS + r)*C1PAD + 128 + c8] = z;
    }
    return;
  }

  if(blk < MS_BASE){
    // ---- weight prep into MFMA fragment order (+ zero replicated stats) ----
    int task = (blk - WP_BASE)*256 + t;
    if(task >= WP_TASKS) return;
    if(task >= 8704){
      stats[task - 8704] = 0.f;
      return;
    }
    int layer, of, cs, ln, ncs; size_t base;
    if(task < 2560){ layer=0; ncs=5; base=0;     int r=task;      of=r/320; r%=320; cs=r>>6; ln=r&63; }
    else if(task < 4608){ layer=1; ncs=4; base=20480; int r=task-2560; of=r>>8; r&=255; cs=r>>6; ln=r&63; }
    else { layer=2; ncs=4; base=36864; int r=task-4608; of=r>>8; r&=255; cs=r>>6; ln=r&63; }
    int o = of*16 + (ln&15);
    s16x8 vals;
    #pragma unroll
    for(int i=0;i<8;++i){
      int c = cs*32 + (ln>>4)*8 + i;
      float v = 0.f;
      if(layer==0){
        if(c<128) v = w1[o*131 + c + 3];
        else if(c<131) v = w1[o*131 + (c-128)];
      } else if(layer==1){
        if(c<128) v = w2[o*128 + c];
      } else {
        if(c<128) v = w3[o*128 + c];
      }
      vals[i]=(short)f2bf(v);
    }
    *(s16x8*)&wfrag[base + ((size_t)(of*ncs + cs)*64 + ln)*8] = vals;
    return;
  }

  {
    // ---- time_emb slice (float4) + style copy ----
    const int mb = blk - MS_BASE;
    #pragma unroll 4
    for(int i=0;i<16;++i){
      int q = mb*4096 + i*256 + t;
      int f = q*4;
      int bb = f>>16, c = (f>>10)&63, s = f&1023;
      *(float4*)&out_time[f] = *(const float4*)&time_emb[((size_t)bb*64 + c)*NPTS + s];
    }
    if(mb==0){ out_style[t]=style[t]; out_style[256+t]=style[256+t]; }
  }
}

// ---------------- ball query: one wave per (b,s) ----------------
__global__ __launch_bounds__(256) void k_ballq(const float* __restrict__ coords,
                                               const float* __restrict__ centers,
                                               int* __restrict__ nidx){
  const int gw = (blockIdx.x*256 + threadIdx.x) >> 6;
  const int lane = threadIdx.x & 63;
  const int wl = (threadIdx.x >> 6);
  const int b = gw >> 10, s = gw & (NS-1);
  const float* cb = coords + (size_t)b*3*NPTS;
  const float cx = centers[(size_t)(b*3+0)*NS+s];
  const float cy = centers[(size_t)(b*3+1)*NS+s];
  const float cz = centers[(size_t)(b*3+2)*NS+s];
  __shared__ int slots[4][NK];
  int cnt = 0;
  for(int base=0; base<NPTS && cnt<NK; base+=64){
    int p = base + lane;
    float d2 = exact_d2(cb[p], cb[NPTS+p], cb[2*NPTS+p], cx,cy,cz);
    bool valid = d2 < 0.0225f;
    unsigned long long mask = __ballot(valid);
    int pos = cnt + (int)__popcll(mask & ((1ull<<lane)-1ull));
    if(valid && pos < NK) slots[wl][pos] = p;
    cnt += (int)__popcll(mask);
  }
  __syncthreads();
  int first = slots[wl][0];
  if(lane < NK){
    int v = (lane < cnt) ? slots[wl][lane] : first;
    nidx[((size_t)b*NS + s)*NK + lane] = v;
  }
}

// ---------------- GEMM1: fused gather + 131->128 MFMA + stats ----------------
__global__ __launch_bounds__(256) void k_gemm1(const unsigned short* __restrict__ featT,
    const int* __restrict__ nidx, const float* __restrict__ coords,
    const float* __restrict__ centers, const unsigned short* __restrict__ wfrag,
    const float* __restrict__ bias, unsigned short* __restrict__ yout,
    float* __restrict__ stats){
  const int b=blockIdx.y, mt=blockIdx.x;
  const int m0=mt*64;
  const int t=threadIdx.x, lane=t&63, wid=t>>6;
  __shared__ unsigned short xs[64][168];
  __shared__ unsigned short ys[64][136];
  __shared__ int pidx[64];
  __shared__ float cenS[2][3];
  __shared__ float wsum[2][8][4];
  if(t<64) pidx[t]=nidx[(size_t)b*MTOT + m0 + t];
  if(t>=64 && t<70){ int u=t-64; int j=u/3, c=u%3; cenS[j][c]=centers[((size_t)b*3+c)*NS + (m0>>5)+j]; }
  __syncthreads();
  for(int q=t;q<1280;q+=256){
    int r=q&63, ch=q>>6;
    *(s16x8*)&xs[r][ch*8] = *(const s16x8*)&featT[((size_t)b*NPTS + pidx[r])*C1PAD + ch*8];
  }
  __syncthreads();
  if(t<64){
    int p=pidx[t]; int sj=t>>5;
    float n0=__fadd_rn(coords[((size_t)b*3+0)*NPTS+p],-cenS[sj][0]);
    float n1=__fadd_rn(coords[((size_t)b*3+1)*NPTS+p],-cenS[sj][1]);
    float n2=__fadd_rn(coords[((size_t)b*3+2)*NPTS+p],-cenS[sj][2]);
    s16x4 nc={(short)f2bf(n0),(short)f2bf(n1),(short)f2bf(n2),0};
    *(s16x4*)&xs[t][128]=nc;
  }
  __syncthreads();
  f32x4 acc[8];
  #pragma unroll
  for(int i=0;i<8;++i) acc[i]=(f32x4){0.f,0.f,0.f,0.f};
  const unsigned short* xrow=&xs[wid*16+(lane&15)][0];
  #pragma unroll
  for(int cs=0;cs<5;++cs){
    s16x8 bfv=*(const s16x8*)&xrow[cs*32+(lane>>4)*8];
    #pragma unroll
    for(int of=0;of<8;++of){
      s16x8 afv=*(const s16x8*)&wfrag[((size_t)(of*5+cs)*64+lane)*8];
      acc[of]=__builtin_amdgcn_mfma_f32_16x16x32_bf16(afv,bfv,acc[of],0,0,0);
    }
  }
  #pragma unroll
  for(int of=0;of<8;++of){
    float ls=0.f,lq=0.f;
    int obase=of*16+((lane>>4)<<2);
    #pragma unroll
    for(int r=0;r<4;++r){
      float y=acc[of][r]+bias[obase+r];
      ys[wid*16+(lane&15)][obase+r]=f2bf(y);
      ls+=y; lq+=y*y;
    }
    ls=wave_fsum_dpp(ls); lq=wave_fsum_dpp(lq);
    if(lane==63){ wsum[0][of][wid]=ls; wsum[1][of][wid]=lq; }
  }
  __syncthreads();
  for(int q=t;q<1024;q+=256){
    int r=q&63, ch=q>>6;
    *(s16x8*)&yout[((size_t)b*MTOT+m0+r)*O1 + ch*8] = *(const s16x8*)&ys[r][ch*8];
  }
  if(t<8){
    float s1v=wsum[0][t][0]+wsum[0][t][1]+wsum[0][t][2]+wsum[0][t][3];
    float s2v=wsum[1][t][0]+wsum[1][t][1]+wsum[1][t][2]+wsum[1][t][3];
    int rep = mt & (SREP-1);
    atomicAdd(&stats[(((0*BATCH+b)*8+t)*SREP+rep)*2+0],s1v);
    atomicAdd(&stats[(((0*BATCH+b)*8+t)*SREP+rep)*2+1],s2v);
  }
}

// ---------------- GEMM2/3: stats->norm+SiLU on load, 128->O MFMA + stats ----------------
// LAYER==1: writes y (bf16), one phase. LAYER==2: two phases (o-halves) sharing xs; writes k-min/max.
template<int LAYER>
__global__ __launch_bounds__(256) void k_gemm23(const unsigned short* __restrict__ xin,
    const unsigned short* __restrict__ wfrag, const float* __restrict__ bias,
    const float* __restrict__ stats, const float* __restrict__ gprev,
    const float* __restrict__ beprev, unsigned short* __restrict__ yout,
    float* __restrict__ ymm, float* __restrict__ statsOut){
  const int b=blockIdx.y, mt=blockIdx.x;
  const int m0=mt*64;
  const int t=threadIdx.x, lane=t&63, wid=t>>6;
  __shared__ unsigned short xs[64][136];
  __shared__ unsigned short ys[64][136];
  __shared__ float lsc[CIN], lsh[CIN];
  __shared__ float wsum[2][8][4];
  if(t<CIN){
    int g = t>>4;                               // input layer cpg = 16
    const float cnt = 16.0f*NS*NK;
    float s1,s2; stats_sum(stats, LAYER-1, b, g, s1, s2);
    float mu=s1/cnt, var=s2/cnt-mu*mu;
    float sc=gprev[t]*rsqrtf(var+GN_EPS);
    lsc[t]=sc; lsh[t]=beprev[t]-mu*sc;
  }
  __syncthreads();
  for(int q=t;q<1024;q+=256){
    int r=q&63, ch=q>>6;
    s16x8 v = *(const s16x8*)&xin[((size_t)b*MTOT + m0 + r)*CIN + ch*8];
    s16x8 o;
    #pragma unroll
    for(int i=0;i<8;++i){
      int c=ch*8+i;
      float x = bf2f((unsigned short)v[i]);
      x = x*lsc[c] + lsh[c];
      o[i]=(short)f2bf(x*fast_sigmoid(x));
    }
    *(s16x8*)&xs[r][ch*8]=o;
  }
  __syncthreads();
  const unsigned short* xrow=&xs[wid*16+(lane&15)][0];
  s16x8 bfv[4];
  #pragma unroll
  for(int cs=0;cs<4;++cs) bfv[cs]=*(const s16x8*)&xrow[cs*32+(lane>>4)*8];
  const int NPH=(LAYER==2)?2:1;
  #pragma unroll
  for(int ph=0; ph<NPH; ++ph){
    f32x4 acc[8];
    #pragma unroll
    for(int i=0;i<8;++i) acc[i]=(f32x4){0.f,0.f,0.f,0.f};
    #pragma unroll
    for(int cs=0;cs<4;++cs){
      #pragma unroll
      for(int of=0;of<8;++of){
        int ofg=ph*8+of;
        s16x8 afv=*(const s16x8*)&wfrag[((size_t)(ofg*4+cs)*64+lane)*8];
        acc[of]=__builtin_amdgcn_mfma_f32_16x16x32_bf16(afv,bfv[cs],acc[of],0,0,0);
      }
    }
    #pragma unroll
    for(int of=0;of<8;++of){
      float ls=0.f,lq=0.f;
      int lobase=of*16+((lane>>4)<<2);
      #pragma unroll
      for(int r=0;r<4;++r){
        float y=acc[of][r]+bias[ph*128+lobase+r];
        ys[wid*16+(lane&15)][lobase+r]=f2bf(y);
        ls+=y; lq+=y*y;
      }
      ls=wave_fsum_dpp(ls); lq=wave_fsum_dpp(lq);
      if(lane==63){ wsum[0][of][wid]=ls; wsum[1][of][wid]=lq; }
    }
    __syncthreads();
    if constexpr(LAYER==1){
      for(int q=t;q<1024;q+=256){
        int r=q&63, ch=q>>6;
        *(s16x8*)&yout[((size_t)b*MTOT+m0+r)*O1 + ch*8] = *(const s16x8*)&ys[r][ch*8];
      }
    } else {
      // per-(s,c) min/max over 32 k-rows (silu quasiconvex: max silu = max(silu(min), silu(max)))
      int c = t&127, sg = t>>7;
      float mn=3.4e38f, mx=-3.4e38f;
      #pragma unroll 8
      for(int k=0;k<32;++k){
        float v = bf2f(ys[sg*32+k][c]);
        mn=fminf(mn,v); mx=fmaxf(mx,v);
      }
      *(float2*)&ymm[(((size_t)b*NS + mt*2 + sg)*512) + (size_t)(ph*128+c)*2] = make_float2(mn,mx);
    }
    if(t<8){
      float s1v=wsum[0][t][0]+wsum[0][t][1]+wsum[0][t][2]+wsum[0][t][3];
      float s2v=wsum[1][t][0]+wsum[1][t][1]+wsum[1][t][2]+wsum[1][t][3];
      int g = (LAYER==2) ? (ph*4 + (t>>1)) : t;
      int rep = mt & (SREP-1);
      atomicAdd(&statsOut[(((LAYER*BATCH+b)*8+g)*SREP+rep)*2+0],s1v);
      atomicAdd(&statsOut[(((LAYER*BATCH+b)*8+g)*SREP+rep)*2+1],s2v);
    }
    if(ph+1<NPH) __syncthreads();
  }
}

// ---------------- final: norm3+SiLU on (min,max) + transposed coalesced writes ----------------
__global__ __launch_bounds__(256) void k_out(const float* __restrict__ ymm,
    const float* __restrict__ stats, const float* __restrict__ g3,
    const float* __restrict__ be3, float* __restrict__ out){
  const int b=blockIdx.z, st=blockIdx.x;
  const int t=threadIdx.x;
  __shared__ float outT[256][33];
  const int c=t, g=c>>5;                         // layer3 cpg = 32
  const float cnt = 32.0f*NS*NK;
  float s1,s2; stats_sum(stats, 2, b, g, s1, s2);
  float mu=s1/cnt, var=s2/cnt-mu*mu;
  float sc=g3[c]*rsqrtf(var+GN_EPS);
  float sh=be3[c]-mu*sc;
  for(int si=0;si<32;++si){
    int s=st*32+si;
    float2 v=*(const float2*)&ymm[((size_t)b*NS+s)*512 + (size_t)c*2];
    float za=v.x*sc+sh, zb=v.y*sc+sh;
    float fa=za*fast_sigmoid(za);
    float fb=zb*fast_sigmoid(zb);
    outT[c][si]=fmaxf(fa,fb);
  }
  __syncthreads();
  #pragma unroll
  for(int i=0;i<32;++i){
    int row=(t>>5)+i*8;
    out[((size_t)(b*256+row))*NS + st*32 + (t&31)] = outT[row][t&31];
  }
}

extern "C" void kernel_launch(void* const* d_in, const int* in_sizes, int n_in,
                              void* d_out, int out_size, void* d_ws, size_t ws_size,
                              hipStream_t stream){
  const float* features=(const float*)d_in[0];
  const float* coords=(const float*)d_in[1];
  const float* time_emb=(const float*)d_in[2];
  const float* style=(const float*)d_in[3];
  const float* w1=(const float*)d_in[4];
  const float* b1=(const float*)d_in[5];
  const float* g1=(const float*)d_in[6];
  const float* be1=(const float*)d_in[7];
  const float* w2=(const float*)d_in[8];
  const float* b2=(const float*)d_in[9];
  const float* g2=(const float*)d_in[10];
  const float* be2=(const float*)d_in[11];
  const float* w3=(const float*)d_in[12];
  const float* b3=(const float*)d_in[13];
  const float* g3=(const float*)d_in[14];
  const float* be3=(const float*)d_in[15];

  float* out0=(float*)d_out;
  float* out_centers=out0 + (size_t)BATCH*O3*NS;
  float* out_time=out_centers + (size_t)BATCH*3*NS;
  float* out_style=out_time + (size_t)BATCH*64*NS;

  char* ws=(char*)d_ws;
  int* nidx=(int*)(ws + 131072);
  unsigned short* featT=(unsigned short*)(ws + 1179648);
  unsigned short* wfrag=(unsigned short*)(ws + 11796480);
  float* stats=(float*)(ws + 11939840);                  // 96 KB (3×8×8×SREP×2 f32)
  float* ymm=(float*)(ws + 12582912);                    // 16 MB (b,s,256ch × {min,max})
  unsigned short* y1=(unsigned short*)(ws + 33554432);   // 64 MB
  unsigned short* y2=(unsigned short*)(ws + 100663296);  // 64 MB

  k_fused<<<TOTAL_BLOCKS,256,0,stream>>>(coords,features,time_emb,style,w1,w2,w3,
                                         out_centers,out_time,out_style,featT,wfrag,stats);
  k_ballq<<<2048,256,0,stream>>>(coords,out_centers,nidx);
  k_gemm1<<<dim3(512,BATCH),256,0,stream>>>(featT,nidx,coords,out_centers,wfrag,b1,y1,stats);
  k_gemm23<1><<<dim3(512,BATCH),256,0,stream>>>(y1,wfrag+20480,b2,stats,g1,be1,y2,ymm,stats);
  k_gemm23<2><<<dim3(512,BATCH),256,0,stream>>>(y2,wfrag+36864,b3,stats,g2,be2,y2,ymm,stats);
  k_out<<<dim3(32,1,BATCH),256,0,stream>>>(ymm,stats,g3,be3,out0);
}